// Round 2
// baseline (562.877 us; speedup 1.0000x reference)
//
#include <hip/hip_runtime.h>
#include <hip/hip_bf16.h>

#define E_N 640000
#define N_N 40000

static __device__ __forceinline__ unsigned short f2bf(float f) {
  __hip_bfloat16 h = __float2bfloat16(f);
  unsigned short u;
  __builtin_memcpy(&u, &h, 2);
  return u;
}
static __device__ __forceinline__ float bf2f(unsigned short u) {
  return __uint_as_float(((unsigned int)u) << 16);
}
static __device__ __forceinline__ unsigned int fkey(float f) {
  unsigned int b = __float_as_uint(f);
  return (b & 0x80000000u) ? ~b : (b | 0x80000000u);
}
static __device__ __forceinline__ float fdec(unsigned int k) {
  if (k == 0u) return 0.0f;
  return __uint_as_float((k & 0x80000000u) ? (k & 0x7fffffffu) : ~k);
}

// ---------------- Y[n,k,o] = sum_i x[n,i] W[k,i,o], bf16 out ----------------
// tile: 64 nodes x 64 outs per block, one k per blockIdx.y
__global__ __launch_bounds__(256) void ygemm_kernel(
    const float* __restrict__ x, const float* __restrict__ W,
    unsigned short* __restrict__ Y) {
  __shared__ float xl[64 * 68];  // [node][i], row stride 17 float4
  __shared__ float wt[64 * 68];  // [o][i] transposed, row stride 17 float4
  const int k = blockIdx.y;
  const int n0 = blockIdx.x * 64;
  const int t = threadIdx.x;

  {
    const float4* xs = (const float4*)(x + (size_t)n0 * 64);
    #pragma unroll
    for (int r = 0; r < 4; ++r) {
      int e = t + 256 * r;  // 0..1023 float4s
      ((float4*)xl)[(e >> 4) * 17 + (e & 15)] = xs[e];
    }
    const float* Wk = W + (size_t)k * 4096;
    #pragma unroll
    for (int r = 0; r < 16; ++r) {
      int e = t + 256 * r;  // = i*64 + o
      wt[(e & 63) * 68 + (e >> 6)] = Wk[e];
    }
  }
  __syncthreads();

  const int ol = t & 15;        // output lane; this thread owns o = ol + 16*oo
  const int nB = (t >> 4) * 4;  // node group
  float acc[4][4] = {};
  #pragma unroll
  for (int i4 = 0; i4 < 16; ++i4) {
    float4 wv[4];
    #pragma unroll
    for (int oo = 0; oo < 4; ++oo)
      wv[oo] = ((const float4*)wt)[(ol + 16 * oo) * 17 + i4];
    #pragma unroll
    for (int nn = 0; nn < 4; ++nn) {
      float4 xv = ((const float4*)xl)[(nB + nn) * 17 + i4];
      #pragma unroll
      for (int oo = 0; oo < 4; ++oo)
        acc[nn][oo] += xv.x * wv[oo].x + xv.y * wv[oo].y +
                       xv.z * wv[oo].z + xv.w * wv[oo].w;
    }
  }

  #pragma unroll
  for (int nn = 0; nn < 4; ++nn) {
    size_t off = ((size_t)(n0 + nB + nn) * 25 + k) * 64;
    #pragma unroll
    for (int oo = 0; oo < 4; ++oo)
      Y[off + ol + 16 * oo] = f2bf(acc[nn][oo]);
  }
}

// ---------------- edge pass: one wave per edge, atomicMax into keyed agg ----------------
__global__ __launch_bounds__(256) void edge_kernel(
    const unsigned short* __restrict__ Y, const float* __restrict__ ea,
    const int* __restrict__ ei, unsigned int* __restrict__ agg) {
  int wv = blockIdx.x * 4 + (threadIdx.x >> 6);
  int lane = threadIdx.x & 63;
  int s = ei[wv];
  int d = ei[E_N + wv];
  float2 a = ((const float2*)ea)[wv];
  // degree-1 spline basis, K=5: v = a*(K-1), bot = clip(floor(v),0,3)
  float v0 = a.x * 4.0f, v1 = a.y * 4.0f;
  float b0f = fminf(fmaxf(floorf(v0), 0.0f), 3.0f);
  float b1f = fminf(fmaxf(floorf(v1), 0.0f), 3.0f);
  float f0 = v0 - b0f, f1 = v1 - b1f;
  int I0 = (int)b0f * 5 + (int)b1f;  // taps: I0, I0+1, I0+5, I0+6
  const unsigned short* base = Y + (size_t)s * 1600 + I0 * 64 + lane;
  float y0 = bf2f(base[0]);
  float y1 = bf2f(base[64]);
  float y2 = bf2f(base[320]);
  float y3 = bf2f(base[384]);
  float m = (1.0f - f0) * ((1.0f - f1) * y0 + f1 * y1) +
            f0 * ((1.0f - f1) * y2 + f1 * y3);
  atomicMax(agg + (size_t)d * 64 + lane, fkey(m));
}

// ---------------- epilogue: out = dec(agg) + xin@root + bias (+relu) ----------------
__global__ __launch_bounds__(256) void epilogue_kernel(
    const unsigned int* __restrict__ agg, const float* __restrict__ xin,
    const float* __restrict__ root, const float* __restrict__ bias,
    float* __restrict__ out, int relu) {
  __shared__ float xl[4][64];
  int w = threadIdx.x >> 6;
  int lane = threadIdx.x & 63;
  int n = blockIdx.x * 4 + w;
  xl[w][lane] = xin[(size_t)n * 64 + lane];
  __syncthreads();
  float acc = bias[lane];
  #pragma unroll 8
  for (int i = 0; i < 64; ++i)
    acc += xl[w][i] * root[i * 64 + lane];
  float r = fdec(agg[(size_t)n * 64 + lane]) + acc;
  if (relu) r = fmaxf(r, 0.0f);
  out[(size_t)n * 64 + lane] = r;
}

extern "C" void kernel_launch(void* const* d_in, const int* in_sizes, int n_in,
                              void* d_out, int out_size, void* d_ws, size_t ws_size,
                              hipStream_t stream) {
  const float* x = (const float*)d_in[0];
  const int* ei = (const int*)d_in[1];  // harness materializes integers as int32
  const float* ea = (const float*)d_in[2];
  const float* W1 = (const float*)d_in[3];
  const float* root1 = (const float*)d_in[4];
  const float* bias1 = (const float*)d_in[5];
  const float* W2 = (const float*)d_in[6];
  const float* root2 = (const float*)d_in[7];
  const float* bias2 = (const float*)d_in[8];
  float* out = (float*)d_out;

  const size_t yB = (size_t)N_N * 1600 * 2;  // 128,000,000
  const size_t aB = (size_t)N_N * 64 * 4;    //  10,240,000
  const size_t hB = (size_t)N_N * 64 * 4;    //  10,240,000
  if (ws_size < yB + aB + hB) return;        // graceful diagnostic, no OOB

  char* w = (char*)d_ws;
  unsigned short* Y = (unsigned short*)w; w += yB;
  unsigned int* agg = (unsigned int*)w;   w += aB;
  float* h = (float*)w;                   w += hB;

  dim3 blk(256);

  // ---- layer 1 ----
  ygemm_kernel<<<dim3(N_N / 64, 25), blk, 0, stream>>>(x, W1, Y);
  hipMemsetAsync(agg, 0, aB, stream);
  edge_kernel<<<E_N / 4, blk, 0, stream>>>(Y, ea, ei, agg);
  epilogue_kernel<<<N_N / 4, blk, 0, stream>>>(agg, x, root1, bias1, h, 1);

  // ---- layer 2 ----
  ygemm_kernel<<<dim3(N_N / 64, 25), blk, 0, stream>>>(h, W2, Y);
  hipMemsetAsync(agg, 0, aB, stream);
  edge_kernel<<<E_N / 4, blk, 0, stream>>>(Y, ea, ei, agg);
  epilogue_kernel<<<N_N / 4, blk, 0, stream>>>(agg, h, root2, bias2, out, 0);
}

// Round 3
// 426.250 us; speedup vs baseline: 1.3205x; 1.3205x over previous
//
#include <hip/hip_runtime.h>
#include <hip/hip_bf16.h>

#define E_N 640000
#define N_N 40000

typedef __attribute__((ext_vector_type(8))) short short8;
typedef __attribute__((ext_vector_type(4))) float f32x4;

static __device__ __forceinline__ unsigned short f2bf(float f) {
  __hip_bfloat16 h = __float2bfloat16(f);
  unsigned short u;
  __builtin_memcpy(&u, &h, 2);
  return u;
}
static __device__ __forceinline__ float bf2f(unsigned short u) {
  return __uint_as_float(((unsigned int)u) << 16);
}
static __device__ __forceinline__ unsigned int fkey(float f) {
  unsigned int b = __float_as_uint(f);
  return (b & 0x80000000u) ? ~b : (b | 0x80000000u);
}
static __device__ __forceinline__ float fdec(unsigned int k) {
  if (k == 0u) return 0.0f;
  return __uint_as_float((k & 0x80000000u) ? (k & 0x7fffffffu) : ~k);
}

// ---------------- Wt[k][o][i] = bf16(W[k][i][o]) ----------------
__global__ __launch_bounds__(256) void wtrans_kernel(
    const float* __restrict__ W, unsigned short* __restrict__ Wt) {
  int t = blockIdx.x * 256 + threadIdx.x;  // 25*64*64 = 102400
  int k = t >> 12, r = t & 4095, o = r >> 6, i = r & 63;
  Wt[(k << 12) | (o << 6) | i] = f2bf(W[(k << 12) | (i << 6) | o]);
}

// ---------------- Y[n,k,o] via MFMA: C[o][node] = Wt_rows x x_cols ----------------
// block = 256 thr = 4 waves, 64 nodes/block; wave w handles k = w, w+4, ...
__global__ __launch_bounds__(256) void ygemm_kernel(
    const float* __restrict__ x, const unsigned short* __restrict__ Wt,
    unsigned short* __restrict__ Y) {
  const int n0 = blockIdx.x * 64;
  const int w = threadIdx.x >> 6;
  const int l = threadIdx.x & 63;
  const int lr = l & 15;  // col lane (node) / row lane (o) within 16
  const int lh = l >> 4;  // quad

  // B-frags: x[node][i], node = n0+nt*16+lr, i = h*32 + lh*8 + j  (fp32 -> bf16)
  short8 bx[4][2];
  #pragma unroll
  for (int nt = 0; nt < 4; ++nt) {
    const float* xp = x + ((size_t)(n0 + nt * 16 + lr) << 6) + (lh << 3);
    #pragma unroll
    for (int h = 0; h < 2; ++h) {
      float4 lo = *(const float4*)(xp + h * 32);
      float4 hi = *(const float4*)(xp + h * 32 + 4);
      short8 b;
      b[0] = (short)f2bf(lo.x); b[1] = (short)f2bf(lo.y);
      b[2] = (short)f2bf(lo.z); b[3] = (short)f2bf(lo.w);
      b[4] = (short)f2bf(hi.x); b[5] = (short)f2bf(hi.y);
      b[6] = (short)f2bf(hi.z); b[7] = (short)f2bf(hi.w);
      bx[nt][h] = b;
    }
  }

  const f32x4 Z = {0.0f, 0.0f, 0.0f, 0.0f};

  for (int k = w; k < 25; k += 4) {
    const unsigned short* wk = Wt + ((size_t)k << 12);
    // A-frags: Wt[k][o][i], o = ot*16+lr, i = h*32 + lh*8 + j  (16B contiguous)
    short8 aw[4][2];
    #pragma unroll
    for (int ot = 0; ot < 4; ++ot)
      #pragma unroll
      for (int h = 0; h < 2; ++h)
        aw[ot][h] = *(const short8*)(wk + ((ot * 16 + lr) << 6) + (h << 5) + (lh << 3));

    f32x4 acc[4][4];
    #pragma unroll
    for (int ot = 0; ot < 4; ++ot)
      #pragma unroll
      for (int nt = 0; nt < 4; ++nt) {
        acc[ot][nt] = __builtin_amdgcn_mfma_f32_16x16x32_bf16(aw[ot][0], bx[nt][0], Z, 0, 0, 0);
        acc[ot][nt] = __builtin_amdgcn_mfma_f32_16x16x32_bf16(aw[ot][1], bx[nt][1], acc[ot][nt], 0, 0, 0);
      }

    // store: lane covers node = n0+nt*16+lr, o = ot*16 + lh*4 + r  (4 bf16 in-lane)
    #pragma unroll
    for (int ot = 0; ot < 4; ++ot)
      #pragma unroll
      for (int nt = 0; nt < 4; ++nt) {
        int node = n0 + nt * 16 + lr;
        int o = ot * 16 + (lh << 2);
        unsigned int p0 = (unsigned)f2bf(acc[ot][nt][0]) | ((unsigned)f2bf(acc[ot][nt][1]) << 16);
        unsigned int p1 = (unsigned)f2bf(acc[ot][nt][2]) | ((unsigned)f2bf(acc[ot][nt][3]) << 16);
        uint2 p; p.x = p0; p.y = p1;
        *(uint2*)(Y + ((size_t)node * 25 + k) * 64 + o) = p;
      }
  }
}

// ---------------- edge pass: one wave per edge, atomicMax into keyed agg ----------------
__global__ __launch_bounds__(256) void edge_kernel(
    const unsigned short* __restrict__ Y, const float* __restrict__ ea,
    const int* __restrict__ ei, unsigned int* __restrict__ agg) {
  int wv = blockIdx.x * 4 + (threadIdx.x >> 6);
  int lane = threadIdx.x & 63;
  int s = ei[wv];
  int d = ei[E_N + wv];
  float2 a = ((const float2*)ea)[wv];
  float v0 = a.x * 4.0f, v1 = a.y * 4.0f;
  float b0f = fminf(fmaxf(floorf(v0), 0.0f), 3.0f);
  float b1f = fminf(fmaxf(floorf(v1), 0.0f), 3.0f);
  float f0 = v0 - b0f, f1 = v1 - b1f;
  int I0 = (int)b0f * 5 + (int)b1f;  // taps: I0, I0+1, I0+5, I0+6
  const unsigned short* base = Y + (size_t)s * 1600 + I0 * 64 + lane;
  float y0 = bf2f(base[0]);
  float y1 = bf2f(base[64]);
  float y2 = bf2f(base[320]);
  float y3 = bf2f(base[384]);
  float m = (1.0f - f0) * ((1.0f - f1) * y0 + f1 * y1) +
            f0 * ((1.0f - f1) * y2 + f1 * y3);
  atomicMax(agg + (size_t)d * 64 + lane, fkey(m));
}

// ---------------- epilogue: out = dec(agg) + xin@root + bias (+relu) ----------------
__global__ __launch_bounds__(256) void epilogue_kernel(
    const unsigned int* __restrict__ agg, const float* __restrict__ xin,
    const float* __restrict__ root, const float* __restrict__ bias,
    float* __restrict__ out, int relu) {
  __shared__ float xl[4][64];
  int w = threadIdx.x >> 6;
  int lane = threadIdx.x & 63;
  int n = blockIdx.x * 4 + w;
  xl[w][lane] = xin[(size_t)n * 64 + lane];
  __syncthreads();
  float acc = bias[lane];
  #pragma unroll 8
  for (int i = 0; i < 64; ++i)
    acc += xl[w][i] * root[i * 64 + lane];
  float r = fdec(agg[(size_t)n * 64 + lane]) + acc;
  if (relu) r = fmaxf(r, 0.0f);
  out[(size_t)n * 64 + lane] = r;
}

extern "C" void kernel_launch(void* const* d_in, const int* in_sizes, int n_in,
                              void* d_out, int out_size, void* d_ws, size_t ws_size,
                              hipStream_t stream) {
  const float* x = (const float*)d_in[0];
  const int* ei = (const int*)d_in[1];
  const float* ea = (const float*)d_in[2];
  const float* W1 = (const float*)d_in[3];
  const float* root1 = (const float*)d_in[4];
  const float* bias1 = (const float*)d_in[5];
  const float* W2 = (const float*)d_in[6];
  const float* root2 = (const float*)d_in[7];
  const float* bias2 = (const float*)d_in[8];
  float* out = (float*)d_out;

  const size_t yB = (size_t)N_N * 1600 * 2;  // 128,000,000
  const size_t aB = (size_t)N_N * 64 * 4;    //  10,240,000
  const size_t hB = (size_t)N_N * 64 * 4;    //  10,240,000
  if (ws_size < yB + aB + hB) return;

  char* w = (char*)d_ws;
  unsigned short* Y = (unsigned short*)w; w += yB;
  unsigned int* agg = (unsigned int*)w;   w += aB;
  float* h = (float*)w;                   w += hB;
  // Wt lives in the agg region (dead until its memset, 204,800 B << aB)
  unsigned short* Wt = (unsigned short*)agg;

  dim3 blk(256);

  // ---- layer 1 ----
  wtrans_kernel<<<400, blk, 0, stream>>>(W1, Wt);
  ygemm_kernel<<<N_N / 64, blk, 0, stream>>>(x, Wt, Y);
  hipMemsetAsync(agg, 0, aB, stream);
  edge_kernel<<<E_N / 4, blk, 0, stream>>>(Y, ea, ei, agg);
  epilogue_kernel<<<N_N / 4, blk, 0, stream>>>(agg, x, root1, bias1, h, 1);

  // ---- layer 2 ----
  wtrans_kernel<<<400, blk, 0, stream>>>(W2, Wt);
  ygemm_kernel<<<N_N / 64, blk, 0, stream>>>(h, Wt, Y);
  hipMemsetAsync(agg, 0, aB, stream);
  edge_kernel<<<E_N / 4, blk, 0, stream>>>(Y, ea, ei, agg);
  epilogue_kernel<<<N_N / 4, blk, 0, stream>>>(agg, h, root2, bias2, out, 0);
}